// Round 3
// baseline (477.834 us; speedup 1.0000x reference)
//
#include <hip/hip_runtime.h>
#include <hip/hip_bf16.h>
#include <math.h>

#define NN 256
#define NPAIR 32640            // 256*255/2
#define NSEG 16
#define MAT (NN*NN)            // 65536 floats

// float offsets inside d_ws
#define CS_U 0
#define CS_V (2*NPAIR)                 // 65280
#define MATS0 131072                   // 32 leaf matrices (U:0..15, V:16..31)
#define MATS1 (MATS0 + 32*MAT)
#define WBT_OFF (MATS1 + 16*MAT)       // 65536 ushort (bf16 W^T[n][k])

// sweep-group boundaries: group g = sweeps [BD[g], BD[g+1]), ~2040 rotations each
static __device__ const int BD[NSEG+1] =
    {0,9,17,26,35,44,54,64,75,87,100,113,128,145,166,192,255};

typedef __attribute__((ext_vector_type(8))) short short8;
typedef __attribute__((ext_vector_type(4))) float f32x4;

__device__ __forceinline__ short f2bf(float f) {
    __hip_bfloat16 h = __float2bfloat16(f);   // RNE
    return *reinterpret_cast<short*>(&h);
}

// ---------------- 1) cos/sin tables ----------------
__global__ __launch_bounds__(256) void k_sincos(const float* __restrict__ au,
                                                const float* __restrict__ av,
                                                float* __restrict__ ws) {
    int id = blockIdx.x * 256 + threadIdx.x;
    if (id < NPAIR) {
        float s, c;
        sincosf(au[id], &s, &c);
        ws[CS_U + 2*id]     = c;
        ws[CS_U + 2*id + 1] = s;
    } else if (id < 2*NPAIR) {
        int k = id - NPAIR;
        float s, c;
        sincosf(av[k], &s, &c);
        ws[CS_V + 2*k]     = c;
        ws[CS_V + 2*k + 1] = s;
    }
}

// ---------------- 2) segment partial products (register-ri, batched tail) ----
__global__ __launch_bounds__(64) void k_build(const float* __restrict__ ws,
                                              float* __restrict__ mats) {
    int b = blockIdx.x;
    int matid = b >> 6;          // 0=U, 1=V
    int seg   = (b >> 2) & 15;
    int chunk = b & 3;
    int t = threadIdx.x;         // 0..63
    int col = chunk * 64 + t;

    __shared__ float M[NN * 64];
#pragma unroll 4
    for (int r = 0; r < NN; ++r) M[r*64 + t] = (r == col) ? 1.0f : 0.0f;

    const float* cs = ws + (matid ? CS_V : CS_U);
    int i0 = BD[seg], i1 = BD[seg+1];
    int k = 255*i0 - (i0*(i0-1))/2;      // rotations before sweep i0

    for (int i = i0; i < i1; ++i) {
        float ri = M[i*64 + t];
        int j = i + 1;
        for (; j + 8 <= 256; j += 8, k += 8) {
            const float* cp = cs + 2*k;
            float2 c0 = *(const float2*)(cp);
            float2 c1 = *(const float2*)(cp + 2);
            float2 c2 = *(const float2*)(cp + 4);
            float2 c3 = *(const float2*)(cp + 6);
            float2 c4 = *(const float2*)(cp + 8);
            float2 c5 = *(const float2*)(cp + 10);
            float2 c6 = *(const float2*)(cp + 12);
            float2 c7 = *(const float2*)(cp + 14);
            float* Mj = &M[j*64 + t];
            float rj0 = Mj[0];   float rj1 = Mj[64];  float rj2 = Mj[128];
            float rj3 = Mj[192]; float rj4 = Mj[256]; float rj5 = Mj[320];
            float rj6 = Mj[384]; float rj7 = Mj[448];
            float wv;
            wv = c0.y*ri + c0.x*rj0; ri = c0.x*ri - c0.y*rj0; Mj[0]   = wv;
            wv = c1.y*ri + c1.x*rj1; ri = c1.x*ri - c1.y*rj1; Mj[64]  = wv;
            wv = c2.y*ri + c2.x*rj2; ri = c2.x*ri - c2.y*rj2; Mj[128] = wv;
            wv = c3.y*ri + c3.x*rj3; ri = c3.x*ri - c3.y*rj3; Mj[192] = wv;
            wv = c4.y*ri + c4.x*rj4; ri = c4.x*ri - c4.y*rj4; Mj[256] = wv;
            wv = c5.y*ri + c5.x*rj5; ri = c5.x*ri - c5.y*rj5; Mj[320] = wv;
            wv = c6.y*ri + c6.x*rj6; ri = c6.x*ri - c6.y*rj6; Mj[384] = wv;
            wv = c7.y*ri + c7.x*rj7; ri = c7.x*ri - c7.y*rj7; Mj[448] = wv;
        }
        int rem = 256 - j;                 // 0..7, wave-uniform
        if (rem > 0) {
            const float* cp = cs + 2*k;
            float rjs[7];
#pragma unroll
            for (int m = 0; m < 7; ++m)     // batched independent loads
                if (m < rem) rjs[m] = M[(j+m)*64 + t];
#pragma unroll
            for (int m = 0; m < 7; ++m)
                if (m < rem) {
                    float cc = cp[2*m], ss = cp[2*m+1];
                    float wv = ss*ri + cc*rjs[m];
                    ri = cc*ri - ss*rjs[m];
                    M[(j+m)*64 + t] = wv;
                }
            k += rem;
        }
        M[i*64 + t] = ri;
    }

    float* outp = mats + (matid * NSEG + seg) * MAT;
#pragma unroll 4
    for (int r = 0; r < NN; ++r) outp[r*NN + col] = M[r*64 + t];
}

// ---------------- 3) tree fold: C = A @ B, 64x64 tiles, LDS-staged ----------
// product order preserved: A = later segment = in[2p+1], B = in[2p]
__global__ __launch_bounds__(256, 4) void k_fold(const float* __restrict__ in,
                                                 float* __restrict__ out, int nOut) {
    int b = blockIdx.x;
    int m = b >> 4, tile = b & 15;
    int nIn = nOut * 2, side = m / nOut, p = m - side * nOut;
    const float* A = in + (side*nIn + 2*p + 1) * MAT;
    const float* B = in + (side*nIn + 2*p) * MAT;
    float* C = out + m * MAT;
    int r0 = (tile >> 2) * 64, c0 = (tile & 3) * 64;

    __shared__ float As[64][68];   // 17.4 KB each, +4 pad
    __shared__ float Bs[64][68];
    int t = threadIdx.x, tx = t & 15, ty = t >> 4;
    float acc[4][4] = {};

    for (int kt = 0; kt < 4; ++kt) {
        __syncthreads();
#pragma unroll
        for (int ps = 0; ps < 4; ++ps) {
            int rr = (t >> 4) + ps * 16;
            int cc = (t & 15) * 4;
            *(float4*)&As[rr][cc] = *(const float4*)(A + (r0+rr)*NN + kt*64 + cc);
            *(float4*)&Bs[rr][cc] = *(const float4*)(B + (kt*64+rr)*NN + c0 + cc);
        }
        __syncthreads();
#pragma unroll
        for (int k4 = 0; k4 < 16; ++k4) {
            float4 a4[4], b4[4];
#pragma unroll
            for (int rr = 0; rr < 4; ++rr) a4[rr] = *(const float4*)&As[ty*4+rr][k4*4];
#pragma unroll
            for (int kk = 0; kk < 4; ++kk) b4[kk] = *(const float4*)&Bs[k4*4+kk][tx*4];
#pragma unroll
            for (int rr = 0; rr < 4; ++rr) {
                float4 av = a4[rr];
                acc[rr][0] += av.x*b4[0].x + av.y*b4[1].x + av.z*b4[2].x + av.w*b4[3].x;
                acc[rr][1] += av.x*b4[0].y + av.y*b4[1].y + av.z*b4[2].y + av.w*b4[3].y;
                acc[rr][2] += av.x*b4[0].z + av.y*b4[1].z + av.z*b4[2].z + av.w*b4[3].z;
                acc[rr][3] += av.x*b4[0].w + av.y*b4[1].w + av.z*b4[2].w + av.w*b4[3].w;
            }
        }
    }
#pragma unroll
    for (int rr = 0; rr < 4; ++rr) {
        float4 o = {acc[rr][0], acc[rr][1], acc[rr][2], acc[rr][3]};
        *(float4*)(C + (r0+ty*4+rr)*NN + c0 + tx*4) = o;
    }
}

// ------- 4) Wbt[n][i] = bf16( sum_k U[i][k] S[k] V[n][k] ), 256 blocks -------
__global__ __launch_bounds__(256) void k_wmatT(const float* __restrict__ U,
                                               const float* __restrict__ V,
                                               const float* __restrict__ S,
                                               unsigned short* __restrict__ Wbt) {
    int b = blockIdx.x;
    int n0 = (b >> 4) * 16, i0 = (b & 15) * 16;
    int t = threadIdx.x, ti = t & 15, tn = t >> 4;
    __shared__ float Us[16][260];    // U*S rows (i-tile), +4 pad
    __shared__ float Vs[16][260];    // V rows (n-tile)
    {
        int rr = t >> 4, cc = (t & 15) * 16;
#pragma unroll
        for (int q = 0; q < 4; ++q) {
            float4 u = *(const float4*)(U + (i0+rr)*NN + cc + q*4);
            float4 s = *(const float4*)(S + cc + q*4);
            u.x *= s.x; u.y *= s.y; u.z *= s.z; u.w *= s.w;
            *(float4*)&Us[rr][cc+q*4] = u;
            *(float4*)&Vs[rr][cc+q*4] = *(const float4*)(V + (n0+rr)*NN + cc + q*4);
        }
    }
    __syncthreads();
    float acc = 0.f;
#pragma unroll 8
    for (int k4 = 0; k4 < 64; ++k4) {
        float4 uu = *(const float4*)&Us[ti][k4*4];
        float4 vv = *(const float4*)&Vs[tn][k4*4];
        acc += uu.x*vv.x + uu.y*vv.y + uu.z*vv.z + uu.w*vv.w;
    }
    Wbt[(n0+tn)*NN + (i0+ti)] = (unsigned short)f2bf(acc);
}

// ---------------- 5) out = x @ W + bias : bf16 MFMA, x via LDS ---------------
// 512 thr = 8 waves; wave w owns output cols [32w,32w+32), W slice in 64 VGPRs.
// Per tile: x staged ONCE (f32->bf16 during staging) into LDS; all 8 waves
// consume from LDS. Double-buffered; next tile's global loads issued before
// the barrier so HBM latency hides under MFMA (T14).
// dbuf safety with ONE barrier/iter: write(it+2, buf[it&1]) occurs after
// barrier(it+1), which all waves reach only after compute(it) finished.
__global__ __launch_bounds__(512, 4) void k_mm(const float* __restrict__ x,
                                               const unsigned short* __restrict__ Wbt,
                                               const float* __restrict__ bias,
                                               float* __restrict__ out) {
    int t = threadIdx.x;
    int w = t >> 6, l = t & 63, l15 = l & 15, lg = l >> 4;
    int n0 = w * 32;

    __shared__ unsigned short Xs[2][16 * 264];   // 16 rows x 256 bf16, pad 8

    // B-fragments: lane holds col n0+nt*16+l15, k = ks*32 + lg*8 + e
    short8 bfrag[2][8];
#pragma unroll
    for (int nt = 0; nt < 2; ++nt) {
        const unsigned short* wrow = Wbt + (n0 + nt*16 + l15) * NN + lg * 8;
#pragma unroll
        for (int ks = 0; ks < 8; ++ks)
            bfrag[nt][ks] = *(const short8*)(wrow + ks * 32);
    }
    float b0 = bias[n0 + l15];
    float b1 = bias[n0 + 16 + l15];

    int row  = t >> 5;          // 0..15  (staging row)
    int col8 = (t & 31) * 8;    // 0..248 (staging col)

    int tile = blockIdx.x;
    const float* src = x + (long)tile * 4096 + row * NN + col8;
    float4 f0 = *(const float4*)(src);
    float4 f1 = *(const float4*)(src + 4);

    for (int it = 0; it < 16; ++it, tile += 512) {
        int cur = it & 1;
        // convert + LDS write (uses loads issued last iteration)
        short8 h;
        h[0]=f2bf(f0.x); h[1]=f2bf(f0.y); h[2]=f2bf(f0.z); h[3]=f2bf(f0.w);
        h[4]=f2bf(f1.x); h[5]=f2bf(f1.y); h[6]=f2bf(f1.z); h[7]=f2bf(f1.w);
        *(short8*)&Xs[cur][row * 264 + col8] = h;
        // issue next tile's loads (in flight across barrier + compute)
        if (it < 15) {
            const float* s2 = x + (long)(tile + 512) * 4096 + row * NN + col8;
            f0 = *(const float4*)(s2);
            f1 = *(const float4*)(s2 + 4);
        }
        __syncthreads();

        f32x4 acc0 = {0.f,0.f,0.f,0.f}, acc1 = {0.f,0.f,0.f,0.f};
        const unsigned short* xs = &Xs[cur][l15 * 264 + lg * 8];
#pragma unroll
        for (int ks = 0; ks < 8; ++ks) {
            short8 af = *(const short8*)(xs + ks * 32);
            acc0 = __builtin_amdgcn_mfma_f32_16x16x32_bf16(af, bfrag[0][ks], acc0, 0, 0, 0);
            acc1 = __builtin_amdgcn_mfma_f32_16x16x32_bf16(af, bfrag[1][ks], acc1, 0, 0, 0);
        }
        // D: col = lane&15, row = (lane>>4)*4 + reg
        float* op = out + ((long)tile * 16 + lg * 4) * NN + n0 + l15;
#pragma unroll
        for (int r = 0; r < 4; ++r) {
            op[r * NN]      = acc0[r] + b0;
            op[r * NN + 16] = acc1[r] + b1;
        }
    }
}

extern "C" void kernel_launch(void* const* d_in, const int* in_sizes, int n_in,
                              void* d_out, int out_size, void* d_ws, size_t ws_size,
                              hipStream_t stream) {
    const float* x    = (const float*)d_in[0];
    const float* Uw   = (const float*)d_in[1];
    const float* Vw   = (const float*)d_in[2];
    const float* Sw   = (const float*)d_in[3];
    const float* bias = (const float*)d_in[4];
    float* out = (float*)d_out;
    float* ws  = (float*)d_ws;

    k_sincos<<<255, 256, 0, stream>>>(Uw, Vw, ws);
    k_build<<<128, 64, 0, stream>>>(ws, ws + MATS0);
    // fold 16 -> 8 -> 4 -> 2 -> 1 per side (order-preserving tree)
    k_fold<<<2*8*16, 256, 0, stream>>>(ws + MATS0, ws + MATS1, 8);
    k_fold<<<2*4*16, 256, 0, stream>>>(ws + MATS1, ws + MATS0, 4);
    k_fold<<<2*2*16, 256, 0, stream>>>(ws + MATS0, ws + MATS1, 2);
    k_fold<<<2*1*16, 256, 0, stream>>>(ws + MATS1, ws + MATS0, 1);
    // Wbt = bf16( (U S V^T)^T ), [n][k] layout
    k_wmatT<<<256, 256, 0, stream>>>(ws + MATS0, ws + MATS0 + MAT, Sw,
                                     (unsigned short*)(ws + WBT_OFF));
    // out = x @ W + bias (bf16 MFMA, LDS-staged x)
    k_mm<<<512, 512, 0, stream>>>(x, (unsigned short*)(ws + WBT_OFF), bias, out);
}

// Round 4
// 325.550 us; speedup vs baseline: 1.4678x; 1.4678x over previous
//
#include <hip/hip_runtime.h>
#include <hip/hip_bf16.h>
#include <math.h>

#define NN 256
#define NPAIR 32640            // 256*255/2
#define NSEG 16
#define MAT (NN*NN)            // 65536 floats

// float offsets inside d_ws
#define CS_U 0
#define CS_V (2*NPAIR)                 // 65280
#define MATS0 131072                   // 32 leaf matrices (U:0..15, V:16..31)
#define MATS1 (MATS0 + 32*MAT)
#define WBT_OFF (MATS1 + 16*MAT)       // 65536 ushort (bf16 W^T[n][k])

// sweep-group boundaries: group g = sweeps [BD[g], BD[g+1]), ~2040 rotations each
static __device__ const int BD[NSEG+1] =
    {0,9,17,26,35,44,54,64,75,87,100,113,128,145,166,192,255};

typedef __attribute__((ext_vector_type(8))) short short8;
typedef __attribute__((ext_vector_type(4))) float f32x4;

__device__ __forceinline__ short f2bf(float f) {
    __hip_bfloat16 h = __float2bfloat16(f);   // RNE
    return *reinterpret_cast<short*>(&h);
}

// ---------------- 1) cos/sin tables ----------------
__global__ __launch_bounds__(256) void k_sincos(const float* __restrict__ au,
                                                const float* __restrict__ av,
                                                float* __restrict__ ws) {
    int id = blockIdx.x * 256 + threadIdx.x;
    if (id < NPAIR) {
        float s, c;
        sincosf(au[id], &s, &c);
        ws[CS_U + 2*id]     = c;
        ws[CS_U + 2*id + 1] = s;
    } else if (id < 2*NPAIR) {
        int k = id - NPAIR;
        float s, c;
        sincosf(av[k], &s, &c);
        ws[CS_V + 2*k]     = c;
        ws[CS_V + 2*k + 1] = s;
    }
}

// ---------------- 2) segment partial products (register-ri, batched tail) ----
__global__ __launch_bounds__(64) void k_build(const float* __restrict__ ws,
                                              float* __restrict__ mats) {
    int b = blockIdx.x;
    int matid = b >> 6;          // 0=U, 1=V
    int seg   = (b >> 2) & 15;
    int chunk = b & 3;
    int t = threadIdx.x;         // 0..63
    int col = chunk * 64 + t;

    __shared__ float M[NN * 64];
#pragma unroll 4
    for (int r = 0; r < NN; ++r) M[r*64 + t] = (r == col) ? 1.0f : 0.0f;

    const float* cs = ws + (matid ? CS_V : CS_U);
    int i0 = BD[seg], i1 = BD[seg+1];
    int k = 255*i0 - (i0*(i0-1))/2;      // rotations before sweep i0

    for (int i = i0; i < i1; ++i) {
        float ri = M[i*64 + t];
        int j = i + 1;
        for (; j + 8 <= 256; j += 8, k += 8) {
            const float* cp = cs + 2*k;
            float2 c0 = *(const float2*)(cp);
            float2 c1 = *(const float2*)(cp + 2);
            float2 c2 = *(const float2*)(cp + 4);
            float2 c3 = *(const float2*)(cp + 6);
            float2 c4 = *(const float2*)(cp + 8);
            float2 c5 = *(const float2*)(cp + 10);
            float2 c6 = *(const float2*)(cp + 12);
            float2 c7 = *(const float2*)(cp + 14);
            float* Mj = &M[j*64 + t];
            float rj0 = Mj[0];   float rj1 = Mj[64];  float rj2 = Mj[128];
            float rj3 = Mj[192]; float rj4 = Mj[256]; float rj5 = Mj[320];
            float rj6 = Mj[384]; float rj7 = Mj[448];
            float wv;
            wv = c0.y*ri + c0.x*rj0; ri = c0.x*ri - c0.y*rj0; Mj[0]   = wv;
            wv = c1.y*ri + c1.x*rj1; ri = c1.x*ri - c1.y*rj1; Mj[64]  = wv;
            wv = c2.y*ri + c2.x*rj2; ri = c2.x*ri - c2.y*rj2; Mj[128] = wv;
            wv = c3.y*ri + c3.x*rj3; ri = c3.x*ri - c3.y*rj3; Mj[192] = wv;
            wv = c4.y*ri + c4.x*rj4; ri = c4.x*ri - c4.y*rj4; Mj[256] = wv;
            wv = c5.y*ri + c5.x*rj5; ri = c5.x*ri - c5.y*rj5; Mj[320] = wv;
            wv = c6.y*ri + c6.x*rj6; ri = c6.x*ri - c6.y*rj6; Mj[384] = wv;
            wv = c7.y*ri + c7.x*rj7; ri = c7.x*ri - c7.y*rj7; Mj[448] = wv;
        }
        int rem = 256 - j;                 // 0..7, wave-uniform
        if (rem > 0) {
            const float* cp = cs + 2*k;
            float rjs[7];
#pragma unroll
            for (int m = 0; m < 7; ++m)     // batched independent loads
                if (m < rem) rjs[m] = M[(j+m)*64 + t];
#pragma unroll
            for (int m = 0; m < 7; ++m)
                if (m < rem) {
                    float cc = cp[2*m], ss = cp[2*m+1];
                    float wv = ss*ri + cc*rjs[m];
                    ri = cc*ri - ss*rjs[m];
                    M[(j+m)*64 + t] = wv;
                }
            k += rem;
        }
        M[i*64 + t] = ri;
    }

    float* outp = mats + (matid * NSEG + seg) * MAT;
#pragma unroll 4
    for (int r = 0; r < NN; ++r) outp[r*NN + col] = M[r*64 + t];
}

// ---------------- 3) tree fold: C = A @ B, register-only, XCD-affine --------
// 8x64 output tile per 256-thread block; thread owns 1x2 outputs.
// 20 independent global loads batched per k-step (no LDS, no barriers).
// Block id: m = bid & (np2-1)  -> all 128 tiles of a product land on the
// same XCD (bid%8 == m%8 since tile stride np2 is a multiple of 8 for
// np2=16,8; 2 XCDs for np2=4, 4 for np2=2) => product panels fetched once
// per L2, not once per block.
// Product order preserved: A = later segment = in[2p+1], B = in[2p].
__global__ __launch_bounds__(256) void k_fold(const float* __restrict__ in,
                                              float* __restrict__ out,
                                              int nOut, int lg) {
    int b = blockIdx.x;
    int np2 = 2 * nOut;
    int m    = b & (np2 - 1);       // output matrix id (XCD-affine)
    int tile = b >> lg;             // 0..127 = 32 rowtiles x 4 coltiles
    int side = (m >= nOut) ? 1 : 0;
    int q = m - side * nOut;
    const float* A = in + (side*np2 + 2*q + 1) * MAT;
    const float* B = in + (side*np2 + 2*q) * MAT;
    float* C = out + m * MAT;

    int r = (tile >> 2) * 8 + (threadIdx.x >> 5);
    int c = (tile & 3) * 64 + (threadIdx.x & 31) * 2;

    float accx = 0.f, accy = 0.f;
    const float* Ar = A + r * NN;
    for (int k0 = 0; k0 < NN; k0 += 16) {
        float4 a4[4];
#pragma unroll
        for (int u = 0; u < 4; ++u) a4[u] = *(const float4*)(Ar + k0 + u*4);
        float2 b2[16];
#pragma unroll
        for (int kk = 0; kk < 16; ++kk) b2[kk] = *(const float2*)(B + (k0+kk)*NN + c);
#pragma unroll
        for (int kk = 0; kk < 16; ++kk) {
            float av = ((const float*)a4)[kk];
            accx = fmaf(av, b2[kk].x, accx);
            accy = fmaf(av, b2[kk].y, accy);
        }
    }
    float2 o = {accx, accy};
    *(float2*)(C + r * NN + c) = o;
}

// ------- 4) Wbt[n][i] = bf16( sum_k U[i][k] S[k] V[n][k] ), 256 blocks -------
__global__ __launch_bounds__(256) void k_wmatT(const float* __restrict__ U,
                                               const float* __restrict__ V,
                                               const float* __restrict__ S,
                                               unsigned short* __restrict__ Wbt) {
    int b = blockIdx.x;
    int n0 = (b >> 4) * 16, i0 = (b & 15) * 16;
    int t = threadIdx.x, ti = t & 15, tn = t >> 4;
    __shared__ float Us[16][260];    // U*S rows (i-tile), +4 pad
    __shared__ float Vs[16][260];    // V rows (n-tile)
    {
        int rr = t >> 4, cc = (t & 15) * 16;
#pragma unroll
        for (int q = 0; q < 4; ++q) {
            float4 u = *(const float4*)(U + (i0+rr)*NN + cc + q*4);
            float4 s = *(const float4*)(S + cc + q*4);
            u.x *= s.x; u.y *= s.y; u.z *= s.z; u.w *= s.w;
            *(float4*)&Us[rr][cc+q*4] = u;
            *(float4*)&Vs[rr][cc+q*4] = *(const float4*)(V + (n0+rr)*NN + cc + q*4);
        }
    }
    __syncthreads();
    float acc = 0.f;
#pragma unroll 8
    for (int k4 = 0; k4 < 64; ++k4) {
        float4 uu = *(const float4*)&Us[ti][k4*4];
        float4 vv = *(const float4*)&Vs[tn][k4*4];
        acc += uu.x*vv.x + uu.y*vv.y + uu.z*vv.z + uu.w*vv.w;
    }
    Wbt[(n0+tn)*NN + (i0+ti)] = (unsigned short)f2bf(acc);
}

// ---------------- 5) out = x @ W + bias : bf16 MFMA, x via LDS ---------------
// 512 thr = 8 waves; wave w owns output cols [32w,32w+32), W slice in 64 VGPRs.
// Per tile: x staged ONCE (f32->bf16 during staging) into LDS; all 8 waves
// consume from LDS. Double-buffered; next tile's global loads issued before
// the barrier so HBM latency hides under MFMA (T14).
__global__ __launch_bounds__(512, 4) void k_mm(const float* __restrict__ x,
                                               const unsigned short* __restrict__ Wbt,
                                               const float* __restrict__ bias,
                                               float* __restrict__ out) {
    int t = threadIdx.x;
    int w = t >> 6, l = t & 63, l15 = l & 15, lg = l >> 4;
    int n0 = w * 32;

    __shared__ unsigned short Xs[2][16 * 264];   // 16 rows x 256 bf16, pad 8

    // B-fragments: lane holds col n0+nt*16+l15, k = ks*32 + lg*8 + e
    short8 bfrag[2][8];
#pragma unroll
    for (int nt = 0; nt < 2; ++nt) {
        const unsigned short* wrow = Wbt + (n0 + nt*16 + l15) * NN + lg * 8;
#pragma unroll
        for (int ks = 0; ks < 8; ++ks)
            bfrag[nt][ks] = *(const short8*)(wrow + ks * 32);
    }
    float b0 = bias[n0 + l15];
    float b1 = bias[n0 + 16 + l15];

    int row  = t >> 5;          // 0..15  (staging row)
    int col8 = (t & 31) * 8;    // 0..248 (staging col)

    int tile = blockIdx.x;
    const float* src = x + (long)tile * 4096 + row * NN + col8;
    float4 f0 = *(const float4*)(src);
    float4 f1 = *(const float4*)(src + 4);

    for (int it = 0; it < 16; ++it, tile += 512) {
        int cur = it & 1;
        // convert + LDS write (uses loads issued last iteration)
        short8 h;
        h[0]=f2bf(f0.x); h[1]=f2bf(f0.y); h[2]=f2bf(f0.z); h[3]=f2bf(f0.w);
        h[4]=f2bf(f1.x); h[5]=f2bf(f1.y); h[6]=f2bf(f1.z); h[7]=f2bf(f1.w);
        *(short8*)&Xs[cur][row * 264 + col8] = h;
        // issue next tile's loads (in flight across barrier + compute)
        if (it < 15) {
            const float* s2 = x + (long)(tile + 512) * 4096 + row * NN + col8;
            f0 = *(const float4*)(s2);
            f1 = *(const float4*)(s2 + 4);
        }
        __syncthreads();

        f32x4 acc0 = {0.f,0.f,0.f,0.f}, acc1 = {0.f,0.f,0.f,0.f};
        const unsigned short* xs = &Xs[cur][l15 * 264 + lg * 8];
#pragma unroll
        for (int ks = 0; ks < 8; ++ks) {
            short8 af = *(const short8*)(xs + ks * 32);
            acc0 = __builtin_amdgcn_mfma_f32_16x16x32_bf16(af, bfrag[0][ks], acc0, 0, 0, 0);
            acc1 = __builtin_amdgcn_mfma_f32_16x16x32_bf16(af, bfrag[1][ks], acc1, 0, 0, 0);
        }
        // D: col = lane&15, row = (lane>>4)*4 + reg
        float* op = out + ((long)tile * 16 + lg * 4) * NN + n0 + l15;
#pragma unroll
        for (int r = 0; r < 4; ++r) {
            op[r * NN]      = acc0[r] + b0;
            op[r * NN + 16] = acc1[r] + b1;
        }
    }
}

extern "C" void kernel_launch(void* const* d_in, const int* in_sizes, int n_in,
                              void* d_out, int out_size, void* d_ws, size_t ws_size,
                              hipStream_t stream) {
    const float* x    = (const float*)d_in[0];
    const float* Uw   = (const float*)d_in[1];
    const float* Vw   = (const float*)d_in[2];
    const float* Sw   = (const float*)d_in[3];
    const float* bias = (const float*)d_in[4];
    float* out = (float*)d_out;
    float* ws  = (float*)d_ws;

    k_sincos<<<255, 256, 0, stream>>>(Uw, Vw, ws);
    k_build<<<128, 64, 0, stream>>>(ws, ws + MATS0);
    // fold 16 -> 8 -> 4 -> 2 -> 1 per side (order-preserving tree)
    // ping-pong: MATS0(leaves) -> MATS1 -> MATS0 -> MATS1 -> MATS0(final)
    k_fold<<<16*128, 256, 0, stream>>>(ws + MATS0, ws + MATS1, 8, 4);
    k_fold<<< 8*128, 256, 0, stream>>>(ws + MATS1, ws + MATS0, 4, 3);
    k_fold<<< 4*128, 256, 0, stream>>>(ws + MATS0, ws + MATS1, 2, 2);
    k_fold<<< 2*128, 256, 0, stream>>>(ws + MATS1, ws + MATS0, 1, 1);
    // Wbt = bf16( (U S V^T)^T ), [n][k] layout
    k_wmatT<<<256, 256, 0, stream>>>(ws + MATS0, ws + MATS0 + MAT, Sw,
                                     (unsigned short*)(ws + WBT_OFF));
    // out = x @ W + bias (bf16 MFMA, LDS-staged x)
    k_mm<<<512, 512, 0, stream>>>(x, (unsigned short*)(ws + WBT_OFF), bias, out);
}